// Round 2
// baseline (198.884 us; speedup 1.0000x reference)
//
#include <hip/hip_runtime.h>

#define EPS 1e-6f
#define NSTEP 63   // L = N-1 aggregation steps (first has no NaN-replace)

// gfx950 transcendental builtins (avoid math.h macro clashes):
//   __builtin_amdgcn_logf(x)  -> v_log_f32  = log2(x)
//   __builtin_amdgcn_exp2f(x) -> v_exp_f32  = 2^x
__device__ __forceinline__ float flog2(float x) { return __builtin_amdgcn_logf(x); }
__device__ __forceinline__ float fexp2(float x) { return __builtin_amdgcn_exp2f(x); }

// One thread per row. Params (w_new, a_vec, r, geo) are recomputed per block
// by wave 0 (63 elems, cached in L1/L2 -> negligible) into LDS.
__global__ __launch_bounds__(256, 4)
void vln_kernel(const float* __restrict__ x,
                const float* __restrict__ a_raw,
                const float* __restrict__ w_raw,
                float* __restrict__ out, int B) {
    __shared__ float s_wn[64];
    __shared__ float s_av[64];
    __shared__ float s_r[64];
    __shared__ int   s_geo[64];
    __shared__ int   s_allgeo;

    const int tid = threadIdx.x;

    if (tid < 64) {
        const int li = (tid < NSTEP) ? tid : 0;   // pad with a real element
        float w = w_raw[li];
        float wmin = w, wmax = w;
        #pragma unroll
        for (int off = 32; off > 0; off >>= 1) {
            wmin = fminf(wmin, __shfl_down(wmin, off));
            wmax = fmaxf(wmax, __shfl_down(wmax, off));
        }
        wmin = __shfl(wmin, 0);
        wmax = __shfl(wmax, 0);
        const float denom = fmaxf(wmax - wmin, 1e-8f);
        float wn = fminf(fmaxf((w - wmin) / denom, 0.0f), 1.0f);
        // sigmoid(a)*3-1 via exp2: exp(-a) = 2^(-a*log2(e))
        float ea = fexp2(-a_raw[li] * 1.4426950408889634f);
        float av = 3.0f / (1.0f + ea) - 1.0f;
        float ac = fminf(fmaxf(av, EPS), 1.0f - EPS);
        float r  = (1.0f - 2.0f * ac) / (ac * (1.0f - ac));
        int geo  = (fabsf(r) < 0.001f) ? 1 : 0;
        s_wn[tid] = wn;
        s_av[tid] = av;
        s_r[tid]  = r;
        s_geo[tid] = geo;
        unsigned long long m = __ballot(geo != 0 || tid >= NSTEP);
        if (tid == 0) s_allgeo = (m == ~0ULL) ? 1 : 0;
    }
    __syncthreads();

    const long long row = (long long)blockIdx.x * 256 + tid;
    if (row >= B) return;

    const float4* xr = (const float4*)(x + (size_t)row * 64);

    // prefetch chunk 0 (16 floats)
    float4 nb0 = xr[0], nb1 = xr[1], nb2 = xr[2], nb3 = xr[3];

    const int allgeo = s_allgeo;  // wave-uniform

    if (allgeo) {
        // ---- hot path: pure weighted-geometric scan in log2 domain ----
        float Lacc = 0.0f;
        #pragma unroll
        for (int c = 0; c < 4; ++c) {
            float f[16];
            ((float4*)f)[0] = nb0; ((float4*)f)[1] = nb1;
            ((float4*)f)[2] = nb2; ((float4*)f)[3] = nb3;
            if (c < 3) {  // prefetch next chunk
                nb0 = xr[4*c+4]; nb1 = xr[4*c+5];
                nb2 = xr[4*c+6]; nb3 = xr[4*c+7];
            }
            float l[16];
            #pragma unroll
            for (int k = 0; k < 16; ++k)
                l[k] = flog2(fminf(fmaxf(f[k], EPS), 1.0f));
            #pragma unroll
            for (int k = 0; k < 16; ++k) {
                const int g = 16*c + k;   // global element index
                if (g == 0) { Lacc = l[0]; continue; }
                const float wn = s_wn[g - 1];
                // (1-wn)*Lacc + wn*l  ==  Lacc + wn*(l - Lacc)
                Lacc = fmaf(wn, l[k] - Lacc, Lacc);
            }
        }
        out[row] = fexp2(Lacc);
    } else {
        // ---- general path: per-step uniform branch geo vs power-mean ----
        float Lacc = 0.0f;   // log2 of clipped accumulator
        float lin  = 0.0f;   // linear value if last step was power-mean
        int use_lin = 0;
        #pragma unroll
        for (int c = 0; c < 4; ++c) {
            float f[16];
            ((float4*)f)[0] = nb0; ((float4*)f)[1] = nb1;
            ((float4*)f)[2] = nb2; ((float4*)f)[3] = nb3;
            if (c < 3) {
                nb0 = xr[4*c+4]; nb1 = xr[4*c+5];
                nb2 = xr[4*c+6]; nb3 = xr[4*c+7];
            }
            float l[16];
            #pragma unroll
            for (int k = 0; k < 16; ++k)
                l[k] = flog2(fminf(fmaxf(f[k], EPS), 1.0f));
            #pragma unroll
            for (int k = 0; k < 16; ++k) {
                const int g = 16*c + k;
                if (g == 0) { Lacc = l[0]; continue; }
                const int i = g - 1;      // step index into params
                const float wn = s_wn[i];
                const float lr = l[k];
                if (s_geo[i]) {           // wave-uniform branch
                    Lacc = fmaf(wn, lr - Lacc, Lacc);
                    use_lin = 0;
                } else {
                    const float r = s_r[i];
                    const float pa = fexp2(r * Lacc);   // acc_c^r
                    const float pb = fexp2(r * lr);     // right_c^r
                    const float s  = (1.0f - wn) * pa + wn * pb;
                    float z = fexp2(flog2(s) / r);      // s^(1/r)
                    if (i > 0 && (z != z)) z = s_av[i]; // NaN -> a_i (steps >=1)
                    lin = z; use_lin = 1;
                    Lacc = flog2(fminf(fmaxf(z, EPS), 1.0f));
                }
            }
        }
        out[row] = use_lin ? lin : fexp2(Lacc);
    }
}

extern "C" void kernel_launch(void* const* d_in, const int* in_sizes, int n_in,
                              void* d_out, int out_size, void* d_ws, size_t ws_size,
                              hipStream_t stream) {
    const float* x     = (const float*)d_in[0];
    const float* a_raw = (const float*)d_in[1];
    const float* w_raw = (const float*)d_in[2];
    float* out = (float*)d_out;
    const int B = out_size;                 // 524288 rows (x is B x 64)
    const int blocks = (B + 255) / 256;
    vln_kernel<<<blocks, 256, 0, stream>>>(x, a_raw, w_raw, out, B);
}

// Round 3
// 193.088 us; speedup vs baseline: 1.0300x; 1.0300x over previous
//
#include <hip/hip_runtime.h>

#define EPS 1e-6f
#define NSTEP 63   // L = N-1 aggregation steps

// gfx950 transcendental builtins (avoid math.h macro clashes):
//   __builtin_amdgcn_logf(x)  -> v_log_f32  = log2(x)
//   __builtin_amdgcn_exp2f(x) -> v_exp_f32  = 2^x
__device__ __forceinline__ float flog2(float x) { return __builtin_amdgcn_logf(x); }
__device__ __forceinline__ float fexp2(float x) { return __builtin_amdgcn_exp2f(x); }

// One thread per row. Rows are staged through a per-wave LDS tile so global
// loads are fully coalesced (64 lanes x 16B contiguous = 1KB/instr, 4 lanes
// per 64B line) instead of 256B-strided (64 lines/instr, L1 thrash).
// LDS slot swizzle: 16B slot (row r, colgroup g) -> r*16 + (g ^ (r&15)).
//   store: per 16-lane cluster slots hit all 8 bank-quads twice -> conflict-free
//   read:  lane l reads row l, fixed g: (g^(l&15))%8 covers all quads -> conflict-free
__global__ __launch_bounds__(256, 2)
void vln_kernel(const float* __restrict__ x,
                const float* __restrict__ a_raw,
                const float* __restrict__ w_raw,
                float* __restrict__ out, int B) {
    __shared__ float4 tile[4][1024];   // 4 waves x (64 rows x 16 slots) = 64 KB
    __shared__ float s_wn[64];
    __shared__ float s_av[64];
    __shared__ float s_r[64];
    __shared__ int   s_geo[64];
    __shared__ int   s_allgeo;

    const int tid = threadIdx.x;

    if (tid < 64) {
        const int li = (tid < NSTEP) ? tid : 0;   // pad with a real element
        float w = w_raw[li];
        float wmin = w, wmax = w;
        #pragma unroll
        for (int off = 32; off > 0; off >>= 1) {
            wmin = fminf(wmin, __shfl_down(wmin, off));
            wmax = fmaxf(wmax, __shfl_down(wmax, off));
        }
        wmin = __shfl(wmin, 0);
        wmax = __shfl(wmax, 0);
        const float denom = fmaxf(wmax - wmin, 1e-8f);
        float wn = fminf(fmaxf((w - wmin) / denom, 0.0f), 1.0f);
        float ea = fexp2(-a_raw[li] * 1.4426950408889634f);  // exp(-a)
        float av = 3.0f / (1.0f + ea) - 1.0f;                // sigmoid*3-1
        float ac = fminf(fmaxf(av, EPS), 1.0f - EPS);
        float r  = (1.0f - 2.0f * ac) / (ac * (1.0f - ac));
        int geo  = (fabsf(r) < 0.001f) ? 1 : 0;
        s_wn[tid] = wn;
        s_av[tid] = av;
        s_r[tid]  = r;
        s_geo[tid] = geo;
        unsigned long long m = __ballot(geo != 0 || tid >= NSTEP);
        if (tid == 0) s_allgeo = (m == ~0ULL) ? 1 : 0;
    }
    __syncthreads();

    const int wave = tid >> 6;
    const int lane = tid & 63;
    const long long rowbase = (long long)blockIdx.x * 256 + wave * 64;
    const long long row = rowbase + lane;

    float4 f[16];

    if (rowbase + 64 <= (long long)B) {
        // ---- full tile: coalesced stage through LDS ----
        const float4* g = (const float4*)(x + (size_t)rowbase * 64);
        float4* tl = tile[wave];
        #pragma unroll
        for (int t = 0; t < 16; ++t) {
            float4 v = g[t * 64 + lane];          // 1KB contiguous per instr
            const int r  = t * 4 + (lane >> 4);   // row within tile
            const int gi = lane & 15;             // colgroup
            tl[r * 16 + (gi ^ (r & 15))] = v;
        }
        // wave-private region, wave-synchronous: no __syncthreads needed
        #pragma unroll
        for (int q = 0; q < 16; ++q)
            f[q] = tl[lane * 16 + (q ^ (lane & 15))];
    } else if (row < (long long)B) {
        // ---- ragged tail: direct (uncoalesced) per-row loads ----
        const float4* xr = (const float4*)(x + (size_t)row * 64);
        #pragma unroll
        for (int q = 0; q < 16; ++q) f[q] = xr[q];
    }

    if (row >= (long long)B) return;

    if (s_allgeo) {
        // ---- hot path: weighted-geometric scan in log2 domain ----
        float Lacc = 0.0f;
        #pragma unroll
        for (int q = 0; q < 16; ++q) {
            float el[4];
            el[0] = flog2(fminf(fmaxf(f[q].x, EPS), 1.0f));
            el[1] = flog2(fminf(fmaxf(f[q].y, EPS), 1.0f));
            el[2] = flog2(fminf(fmaxf(f[q].z, EPS), 1.0f));
            el[3] = flog2(fminf(fmaxf(f[q].w, EPS), 1.0f));
            #pragma unroll
            for (int j = 0; j < 4; ++j) {
                const int gidx = 4 * q + j;
                if (gidx == 0) { Lacc = el[0]; continue; }
                const float wn = s_wn[gidx - 1];
                Lacc = fmaf(wn, el[j] - Lacc, Lacc);   // (1-wn)*L + wn*l
            }
        }
        out[row] = fexp2(Lacc);
    } else {
        // ---- general path: per-step uniform branch geo vs power-mean ----
        float Lacc = 0.0f;   // log2 of clipped accumulator
        float lin  = 0.0f;   // linear value if last step was power-mean
        int use_lin = 0;
        #pragma unroll
        for (int q = 0; q < 16; ++q) {
            float el[4];
            el[0] = flog2(fminf(fmaxf(f[q].x, EPS), 1.0f));
            el[1] = flog2(fminf(fmaxf(f[q].y, EPS), 1.0f));
            el[2] = flog2(fminf(fmaxf(f[q].z, EPS), 1.0f));
            el[3] = flog2(fminf(fmaxf(f[q].w, EPS), 1.0f));
            #pragma unroll
            for (int j = 0; j < 4; ++j) {
                const int gidx = 4 * q + j;
                if (gidx == 0) { Lacc = el[0]; continue; }
                const int i = gidx - 1;
                const float wn = s_wn[i];
                const float lr = el[j];
                if (s_geo[i]) {           // wave-uniform branch
                    Lacc = fmaf(wn, lr - Lacc, Lacc);
                    use_lin = 0;
                } else {
                    const float r  = s_r[i];
                    const float pa = fexp2(r * Lacc);   // acc_c^r
                    const float pb = fexp2(r * lr);     // right_c^r
                    const float s  = (1.0f - wn) * pa + wn * pb;
                    float z = fexp2(flog2(s) / r);      // s^(1/r)
                    if (i > 0 && (z != z)) z = s_av[i]; // NaN -> a_i
                    lin = z; use_lin = 1;
                    Lacc = flog2(fminf(fmaxf(z, EPS), 1.0f));
                }
            }
        }
        out[row] = use_lin ? lin : fexp2(Lacc);
    }
}

extern "C" void kernel_launch(void* const* d_in, const int* in_sizes, int n_in,
                              void* d_out, int out_size, void* d_ws, size_t ws_size,
                              hipStream_t stream) {
    const float* x     = (const float*)d_in[0];
    const float* a_raw = (const float*)d_in[1];
    const float* w_raw = (const float*)d_in[2];
    float* out = (float*)d_out;
    const int B = out_size;                 // 524288 rows (x is B x 64)
    const int blocks = (B + 255) / 256;
    vln_kernel<<<blocks, 256, 0, stream>>>(x, a_raw, w_raw, out, B);
}

// Round 4
// 191.606 us; speedup vs baseline: 1.0380x; 1.0077x over previous
//
#include <hip/hip_runtime.h>

#define EPS 1e-6f
#define NSTEP 63   // L = N-1 aggregation steps

// gfx950 builtins (avoid math.h macro clashes):
__device__ __forceinline__ float flog2(float x) { return __builtin_amdgcn_logf(x); }   // v_log_f32 = log2
__device__ __forceinline__ float fexp2(float x) { return __builtin_amdgcn_exp2f(x); }  // v_exp_f32 = 2^x
__device__ __forceinline__ float clampe1(float x) { return __builtin_amdgcn_fmed3f(x, EPS, 1.0f); } // clip to [EPS,1]

// All-geometric case (the hot case: a_raw==0 -> r==0 -> every step geometric):
//   out(row) = 2^( sum_i c_i * log2(clip(x_i)) )
//   c_0 = prod_{j=0..62}(1-wn_j);  c_k = wn_{k-1} * prod_{j=k..62}(1-wn_j)
// Layout: 16 lanes per row, 1 float4 per lane -> fully coalesced, no big LDS
// tile; row sum via 4x __shfl_xor within the 16-lane cluster.
__global__ __launch_bounds__(256, 8)
void vln_kernel(const float* __restrict__ x,
                const float* __restrict__ a_raw,
                const float* __restrict__ w_raw,
                float* __restrict__ out, long long B) {
    __shared__ float s_c[64];
    __shared__ float s_wn[64];
    __shared__ float s_av[64];
    __shared__ float s_r[64];
    __shared__ int   s_geo[64];
    __shared__ int   s_allgeo;

    const int tid = threadIdx.x;

    if (tid < 64) {
        const int li = (tid < NSTEP) ? tid : 0;   // pad with a real element
        float w = w_raw[li];
        float wmin = w, wmax = w;
        #pragma unroll
        for (int off = 32; off > 0; off >>= 1) {
            wmin = fminf(wmin, __shfl_down(wmin, off));
            wmax = fmaxf(wmax, __shfl_down(wmax, off));
        }
        wmin = __shfl(wmin, 0);
        wmax = __shfl(wmax, 0);
        const float denom = fmaxf(wmax - wmin, 1e-8f);
        float wn = fminf(fmaxf((w - wmin) / denom, 0.0f), 1.0f);
        float ea = fexp2(-a_raw[li] * 1.4426950408889634f);  // exp(-a)
        float av = 3.0f / (1.0f + ea) - 1.0f;                // sigmoid*3-1
        float ac = fminf(fmaxf(av, EPS), 1.0f - EPS);
        float r  = (1.0f - 2.0f * ac) / (ac * (1.0f - ac));
        int geo  = (fabsf(r) < 0.001f) ? 1 : 0;
        s_wn[tid] = wn;
        s_av[tid] = av;
        s_r[tid]  = r;
        s_geo[tid] = geo;
        unsigned long long m = __ballot(geo != 0 || tid >= NSTEP);
        if (tid == 0) s_allgeo = (m == ~0ULL) ? 1 : 0;

        // suffix products: S_t = prod_{j=t..62}(1-wn_j)  (S_63 = 1)
        float S = (tid < NSTEP) ? (1.0f - wn) : 1.0f;
        #pragma unroll
        for (int off = 1; off < 64; off <<= 1) {
            float o = __shfl_down(S, off);
            if (tid + off < 64) S *= o;
        }
        float wprev = __shfl_up(wn, 1);                  // wn_{t-1}
        s_c[tid] = (tid == 0) ? S : wprev * S;           // c_t
    }
    __syncthreads();

    const long long total4 = B * 16;                     // float4 elements
    const long long stride = (long long)gridDim.x * blockDim.x;
    long long idx0 = (long long)blockIdx.x * blockDim.x + tid;

    if (s_allgeo) {
        // ---- hot path: dot-product in log2 domain, 16 lanes per row ----
        const int k = tid & 15;                          // colgroup of this lane
        const float c0 = s_c[4 * k + 0];
        const float c1 = s_c[4 * k + 1];
        const float c2 = s_c[4 * k + 2];
        const float c3 = s_c[4 * k + 3];
        const float4* __restrict__ x4 = (const float4*)x;

        for (long long i = idx0; i < total4; i += 2 * stride) {
            const long long i1 = i + stride;
            const bool has1 = (i1 < total4);
            float4 v0 = x4[i];
            float4 v1 = has1 ? x4[i1] : make_float4(1.f, 1.f, 1.f, 1.f);

            float p0 = c0 * flog2(clampe1(v0.x));
            p0 = fmaf(c1, flog2(clampe1(v0.y)), p0);
            p0 = fmaf(c2, flog2(clampe1(v0.z)), p0);
            p0 = fmaf(c3, flog2(clampe1(v0.w)), p0);
            p0 += __shfl_xor(p0, 1);
            p0 += __shfl_xor(p0, 2);
            p0 += __shfl_xor(p0, 4);
            p0 += __shfl_xor(p0, 8);
            if (k == 0) out[i >> 4] = fexp2(p0);

            float p1 = c0 * flog2(clampe1(v1.x));
            p1 = fmaf(c1, flog2(clampe1(v1.y)), p1);
            p1 = fmaf(c2, flog2(clampe1(v1.z)), p1);
            p1 = fmaf(c3, flog2(clampe1(v1.w)), p1);
            p1 += __shfl_xor(p1, 1);
            p1 += __shfl_xor(p1, 2);
            p1 += __shfl_xor(p1, 4);
            p1 += __shfl_xor(p1, 8);
            if (has1 && k == 0) out[i1 >> 4] = fexp2(p1);
        }
    } else {
        // ---- cold general path: one row per thread, serial scan ----
        for (long long row = idx0; row < B; row += stride) {
            const float4* xr = (const float4*)(x + (size_t)row * 64);
            float Lacc = 0.0f;
            float lin  = 0.0f;
            int use_lin = 0;
            #pragma unroll
            for (int q = 0; q < 16; ++q) {
                float4 v = xr[q];
                float el[4];
                el[0] = flog2(clampe1(v.x));
                el[1] = flog2(clampe1(v.y));
                el[2] = flog2(clampe1(v.z));
                el[3] = flog2(clampe1(v.w));
                #pragma unroll
                for (int j = 0; j < 4; ++j) {
                    const int gidx = 4 * q + j;
                    if (gidx == 0) { Lacc = el[0]; continue; }
                    const int i = gidx - 1;
                    const float wn = s_wn[i];
                    const float lr = el[j];
                    if (s_geo[i]) {
                        Lacc = fmaf(wn, lr - Lacc, Lacc);
                        use_lin = 0;
                    } else {
                        const float r  = s_r[i];
                        const float pa = fexp2(r * Lacc);
                        const float pb = fexp2(r * lr);
                        const float s  = (1.0f - wn) * pa + wn * pb;
                        float z = fexp2(flog2(s) / r);
                        if (i > 0 && (z != z)) z = s_av[i];
                        lin = z; use_lin = 1;
                        Lacc = flog2(clampe1(z));
                    }
                }
            }
            out[row] = use_lin ? lin : fexp2(Lacc);
        }
    }
}

extern "C" void kernel_launch(void* const* d_in, const int* in_sizes, int n_in,
                              void* d_out, int out_size, void* d_ws, size_t ws_size,
                              hipStream_t stream) {
    const float* x     = (const float*)d_in[0];
    const float* a_raw = (const float*)d_in[1];
    const float* w_raw = (const float*)d_in[2];
    float* out = (float*)d_out;
    const long long B = out_size;            // 524288 rows (x is B x 64)
    long long total4 = B * 16;
    int blocks = (int)((total4 + 255) / 256);
    if (blocks > 2048) blocks = 2048;        // 8 blocks/CU x 256 CUs, grid-stride
    vln_kernel<<<blocks, 256, 0, stream>>>(x, a_raw, w_raw, out, B);
}